// Round 1
// baseline (343.796 us; speedup 1.0000x reference)
//
#include <hip/hip_runtime.h>
#include <hip/hip_bf16.h>

#define NHEADS 16
#define DKEY   64
#define DMODEL 1024
#define BATCH  2
#define SEQ    2048

using bf16x8 = __bf16 __attribute__((ext_vector_type(8)));
using bf16x4 = __bf16 __attribute__((ext_vector_type(4)));
using f32x4  = float __attribute__((ext_vector_type(4)));

// ---------------------------------------------------------------------------
// W transpose + cast: W[k][n] fp32 -> WT[n][k] bf16   (per z: Wq,Wk,Wv,Wo)
// ---------------------------------------------------------------------------
__global__ __launch_bounds__(256) void wtrans_kernel(
    const float* __restrict__ Wq, const float* __restrict__ Wk,
    const float* __restrict__ Wv, const float* __restrict__ Wo,
    __bf16* __restrict__ WTbase)
{
  const float* W = (blockIdx.z == 0) ? Wq : (blockIdx.z == 1) ? Wk
                   : (blockIdx.z == 2) ? Wv : Wo;
  __bf16* WT = WTbase + (size_t)blockIdx.z * DMODEL * DMODEL;
  __shared__ float tile[64][65];
  const int tid = threadIdx.x;
  const int k0 = blockIdx.x * 64, n0 = blockIdx.y * 64;
  const int cx = tid & 63, ry = tid >> 6;
#pragma unroll
  for (int i = 0; i < 16; ++i) {
    int kl = i * 4 + ry;
    tile[cx][kl] = W[(size_t)(k0 + kl) * DMODEL + n0 + cx];
  }
  __syncthreads();
#pragma unroll
  for (int i = 0; i < 16; ++i) {
    int nl = i * 4 + ry;
    WT[(size_t)(n0 + nl) * DMODEL + k0 + cx] = (__bf16)tile[nl][cx];
  }
}

// ---------------------------------------------------------------------------
// mask (0/1 fp32) -> bitmask, one uint64 per 64 kv positions
// ---------------------------------------------------------------------------
__global__ __launch_bounds__(256) void maskpack_kernel(
    const float* __restrict__ mask, unsigned long long* __restrict__ bits)
{
  const int gtid = blockIdx.x * 256 + threadIdx.x;
  const int w    = gtid >> 6;
  const int lane = threadIdx.x & 63;
  float v = mask[(size_t)w * 64 + lane];
  unsigned long long m = __ballot(v != 0.0f);
  if (lane == 0) bits[w] = m;
}

// ---------------------------------------------------------------------------
// GEMM: C[M=4096][N=1024] = A[4096][1024] @ BT[n][k]^T + bias
// MODE 0: A fp32, out bf16 head-major Qd/Kd [hb][n][64]
// MODE 2: A fp32, out bf16 transposed   Vt  [hb][64][n]
// MODE 3: A bf16, out fp32 row-major    [4096][1024]
// 128x128 tile, BK=32, 4 waves (2x2), reg-staged with XOR-swizzled LDS.
// ---------------------------------------------------------------------------
template<int MODE>
__global__ __launch_bounds__(256, 2) void gemm_kernel(
    const void* __restrict__ Av, const __bf16* __restrict__ BT,
    const float* __restrict__ bias, void* __restrict__ dst)
{
  __shared__ __bf16 sA[128 * 32];   // rows of 32 bf16 = 64B = 4 slots of 16B
  __shared__ __bf16 sB[128 * 32];
  const int tid = threadIdx.x;
  const int lane = tid & 63;
  const int g    = lane >> 4;      // k-group 0..3
  const int l15  = lane & 15;
  const int wid  = tid >> 6;
  const int wr   = wid >> 1, wc = wid & 1;
  const int m0   = blockIdx.x * 128;
  const int n0   = blockIdx.y * 128;

  f32x4 acc[4][4] = {};

  for (int k0 = 0; k0 < DMODEL; k0 += 32) {
    __syncthreads();
#pragma unroll
    for (int cc = 0; cc < 2; ++cc) {
      int ch = cc * 256 + tid;          // 0..511
      int row = ch >> 2, slot = ch & 3; // LDS row, logical 16B slot
      int sw = slot ^ ((row >> 1) & 3); // physical slot (swizzle)
      bf16x8 v;
      if (MODE == 3) {
        const __bf16* A = (const __bf16*)Av;
        v = *(const bf16x8*)(A + (size_t)(m0 + row) * DMODEL + k0 + slot * 8);
      } else {
        const float* A = (const float*)Av;
        const float* p = A + (size_t)(m0 + row) * DMODEL + k0 + slot * 8;
        f32x4 f0 = *(const f32x4*)p;
        f32x4 f1 = *(const f32x4*)(p + 4);
#pragma unroll
        for (int j = 0; j < 4; ++j) { v[j] = (__bf16)f0[j]; v[j + 4] = (__bf16)f1[j]; }
      }
      *(bf16x8*)((char*)sA + row * 64 + sw * 16) = v;

      bf16x8 w = *(const bf16x8*)(BT + (size_t)(n0 + row) * DMODEL + k0 + slot * 8);
      *(bf16x8*)((char*)sB + row * 64 + sw * 16) = w;
    }
    __syncthreads();

    bf16x8 af[4], bfr[4];
#pragma unroll
    for (int mt = 0; mt < 4; ++mt) {
      int row = wr * 64 + mt * 16 + l15;
      af[mt] = *(const bf16x8*)((char*)sA + row * 64 + ((g ^ ((row >> 1) & 3)) * 16));
    }
#pragma unroll
    for (int nt = 0; nt < 4; ++nt) {
      int row = wc * 64 + nt * 16 + l15;
      bfr[nt] = *(const bf16x8*)((char*)sB + row * 64 + ((g ^ ((row >> 1) & 3)) * 16));
    }
#pragma unroll
    for (int mt = 0; mt < 4; ++mt)
#pragma unroll
      for (int nt = 0; nt < 4; ++nt)
        acc[mt][nt] = __builtin_amdgcn_mfma_f32_16x16x32_bf16(af[mt], bfr[nt], acc[mt][nt], 0, 0, 0);
  }

  // epilogue: D row = g*4+reg (m), col = l15 (n)  [m89-verified layout]
#pragma unroll
  for (int nt = 0; nt < 4; ++nt) {
    int gn = n0 + wc * 64 + nt * 16 + l15;
    float bv = bias[gn];
    int h = gn >> 6, d = gn & 63;
#pragma unroll
    for (int mt = 0; mt < 4; ++mt) {
      int gmb = m0 + wr * 64 + mt * 16 + g * 4;  // 4 consecutive rows
      int b  = gmb >> 11;
      int nr = gmb & 2047;
      if (MODE == 3) {
        float* outp = (float*)dst;
#pragma unroll
        for (int r = 0; r < 4; ++r)
          outp[(size_t)(gmb + r) * DMODEL + gn] = acc[mt][nt][r] + bv;
      } else if (MODE == 2) {
        __bf16* outp = (__bf16*)dst;
        bf16x4 pk;
#pragma unroll
        for (int r = 0; r < 4; ++r) pk[r] = (__bf16)(acc[mt][nt][r] + bv);
        *(bf16x4*)(outp + ((size_t)(h * 2 + b) * DKEY + d) * SEQ + nr) = pk;
      } else {
        __bf16* outp = (__bf16*)dst;
#pragma unroll
        for (int r = 0; r < 4; ++r)
          outp[((size_t)(h * 2 + b) * SEQ + nr + r) * DKEY + d] = (__bf16)(acc[mt][nt][r] + bv);
      }
    }
  }
}

// ---------------------------------------------------------------------------
// Flash-style attention. Block = 64 q-rows of one (h,b); 4 waves x 16 rows.
// Quirk (faithful): U = (QK^T/8) * mask  -> masked scores are 0 (exp = 1!),
// so no max-subtraction needed (|U| bounded); plain sum-exp accumulation.
// mask batch index b' = (h*2+b) >> 4  (reference's repeat-vs-head-major quirk)
// ---------------------------------------------------------------------------
__global__ __launch_bounds__(256, 2) void attn_kernel(
    const __bf16* __restrict__ Qd, const __bf16* __restrict__ Kd,
    const __bf16* __restrict__ Vt, const unsigned long long* __restrict__ mbits,
    __bf16* __restrict__ AO)
{
  __shared__ __bf16 sK[64 * 64];      // [kv][dk] rows=128B, 8 slots, XOR-swz
  __shared__ __bf16 sV[64 * 64];      // [dk][kv] rows=128B, XOR-swz
  __shared__ __bf16 sP[4][16 * 64];   // per-wave P [q16][kv64], XOR-swz

  const int tid = threadIdx.x, lane = tid & 63, wid = tid >> 6;
  const int g = lane >> 4, c = lane & 15;
  const int q0 = blockIdx.x * 64;
  const int hb = blockIdx.y;           // h*2+b (head-major)
  const int h = hb >> 1, b = hb & 1;
  const int bp = hb >> 4;              // mask batch (quirk)

  const __bf16* Qbase = Qd + (size_t)hb * SEQ * DKEY;
  const __bf16* Kbase = Kd + (size_t)hb * SEQ * DKEY;
  const __bf16* Vbase = Vt + (size_t)hb * DKEY * SEQ;

  // Q fragments held in registers for the whole block
  const int qr = q0 + wid * 16 + c;
  bf16x8 aq[2];
  aq[0] = *(const bf16x8*)(Qbase + (size_t)qr * DKEY + g * 8);
  aq[1] = *(const bf16x8*)(Qbase + (size_t)qr * DKEY + 32 + g * 8);

  f32x4 o[4] = {};
  float rs[4] = {0.f, 0.f, 0.f, 0.f};

  for (int kv0 = 0; kv0 < SEQ; kv0 += 64) {
    __syncthreads();
    // stage K and V tiles (8KB each), source pre-swizzled so LDS is read-swz
#pragma unroll
    for (int c2 = 0; c2 < 2; ++c2) {
      int ch = c2 * 256 + tid;
      int row = ch >> 3, sl = ch & 7;
      bf16x8 v = *(const bf16x8*)(Kbase + (size_t)(kv0 + row) * DKEY + ((sl ^ (row & 7)) * 8));
      *(bf16x8*)((char*)sK + ch * 16) = v;
      bf16x8 w = *(const bf16x8*)(Vbase + (size_t)row * SEQ + kv0 + ((sl ^ (row & 7)) * 8));
      *(bf16x8*)((char*)sV + ch * 16) = w;
    }
    __syncthreads();

    unsigned long long mw[4];
#pragma unroll
    for (int r = 0; r < 4; ++r) {
      int q = q0 + wid * 16 + g * 4 + r;
      mw[r] = mbits[((size_t)bp * SEQ + q) * 32 + (kv0 >> 6)];
    }

    // QK^T -> scale -> mask-multiply -> exp -> P (bf16, per-wave LDS)
#pragma unroll
    for (int t = 0; t < 4; ++t) {
      f32x4 u = {0.f, 0.f, 0.f, 0.f};
#pragma unroll
      for (int kk = 0; kk < 2; ++kk) {
        int row = t * 16 + c;
        bf16x8 kf = *(const bf16x8*)((char*)sK + row * 128 + (((g + kk * 4) ^ (row & 7)) * 16));
        u = __builtin_amdgcn_mfma_f32_16x16x32_bf16(aq[kk], kf, u, 0, 0, 0);
      }
#pragma unroll
      for (int r = 0; r < 4; ++r) {
        int col = t * 16 + c;
        float s = u[r] * 0.125f;                    // /sqrt(64)
        s = ((mw[r] >> col) & 1ULL) ? s : 0.0f;     // faithful mask-multiply
        float p = __expf(s);                        // masked -> exp(0)=1
        rs[r] += p;
        int qrl = g * 4 + r;
        int sp = (col >> 3) ^ (qrl & 7);
        *(__bf16*)((char*)&sP[wid][0] + qrl * 128 + sp * 16 + (col & 7) * 2) = (__bf16)p;
      }
    }
    asm volatile("s_waitcnt lgkmcnt(0)" ::: "memory");  // P writes -> reads (same wave)

    // PV: O += P @ V
    bf16x8 ap[2];
#pragma unroll
    for (int kk = 0; kk < 2; ++kk) {
      int sp = (kk * 4 + g) ^ (c & 7);
      ap[kk] = *(const bf16x8*)((char*)&sP[wid][0] + c * 128 + sp * 16);
    }
#pragma unroll
    for (int dt = 0; dt < 4; ++dt) {
#pragma unroll
      for (int kk = 0; kk < 2; ++kk) {
        int row = dt * 16 + c;
        bf16x8 vf = *(const bf16x8*)((char*)sV + row * 128 + (((kk * 4 + g) ^ (row & 7)) * 16));
        o[dt] = __builtin_amdgcn_mfma_f32_16x16x32_bf16(ap[kk], vf, o[dt], 0, 0, 0);
      }
    }
  }

  // row-sum reduce across the 16-lane group (cols live across lanes)
#pragma unroll
  for (int r = 0; r < 4; ++r) {
    float v = rs[r];
    v += __shfl_xor(v, 1, 16);
    v += __shfl_xor(v, 2, 16);
    v += __shfl_xor(v, 4, 16);
    v += __shfl_xor(v, 8, 16);
    rs[r] = v;
  }

  // AO[b][q][h*64+dk] bf16 (layout the final GEMM consumes directly)
#pragma unroll
  for (int dt = 0; dt < 4; ++dt) {
#pragma unroll
    for (int r = 0; r < 4; ++r) {
      int q = q0 + wid * 16 + g * 4 + r;
      int dk = dt * 16 + c;
      AO[((size_t)b * SEQ + q) * DMODEL + h * 64 + dk] = (__bf16)(o[dt][r] / rs[r]);
    }
  }
}

// ---------------------------------------------------------------------------
extern "C" void kernel_launch(void* const* d_in, const int* in_sizes, int n_in,
                              void* d_out, int out_size, void* d_ws, size_t ws_size,
                              hipStream_t stream)
{
  (void)in_sizes; (void)n_in; (void)out_size; (void)ws_size;
  const float* Q    = (const float*)d_in[0];
  const float* V    = (const float*)d_in[1];   // note: V before K in inputs
  const float* K    = (const float*)d_in[2];
  const float* mask = (const float*)d_in[3];
  const float* Wq   = (const float*)d_in[4];
  const float* bq   = (const float*)d_in[5];
  const float* Wk   = (const float*)d_in[6];
  const float* bk   = (const float*)d_in[7];
  const float* Wv   = (const float*)d_in[8];
  const float* bv   = (const float*)d_in[9];
  const float* Wo   = (const float*)d_in[10];
  const float* bo   = (const float*)d_in[11];
  float* out = (float*)d_out;

  char* ws = (char*)d_ws;
  const size_t MB = 1024 * 1024;
  __bf16* WT = (__bf16*)(ws);              // 4 x 2MB (bf16 [n][k])
  __bf16* Qd = (__bf16*)(ws + 8 * MB);     // 8MB  [hb][n][64]
  __bf16* Kd = (__bf16*)(ws + 16 * MB);    // 8MB  [hb][n][64]
  __bf16* Vt = (__bf16*)(ws + 24 * MB);    // 8MB  [hb][64][n]
  __bf16* AO = (__bf16*)(ws + 32 * MB);    // 8MB  [b][n][1024]
  unsigned long long* mbits = (unsigned long long*)(ws + 40 * MB); // 1MB

  wtrans_kernel<<<dim3(16, 16, 4), 256, 0, stream>>>(Wq, Wk, Wv, Wo, WT);
  maskpack_kernel<<<dim3(32768), 256, 0, stream>>>(mask, mbits);
  gemm_kernel<0><<<dim3(32, 8), 256, 0, stream>>>(Q, WT + (size_t)0 * MB, bq, Qd);
  gemm_kernel<0><<<dim3(32, 8), 256, 0, stream>>>(K, WT + (size_t)1 * MB, bk, Kd);
  gemm_kernel<2><<<dim3(32, 8), 256, 0, stream>>>(V, WT + (size_t)2 * MB, bv, Vt);
  attn_kernel<<<dim3(32, 32), 256, 0, stream>>>(Qd, Kd, Vt, mbits, AO);
  gemm_kernel<3><<<dim3(32, 8), 256, 0, stream>>>(AO, WT + (size_t)3 * MB, bo, out);
}

// Round 7
// 290.819 us; speedup vs baseline: 1.1822x; 1.1822x over previous
//
#include <hip/hip_runtime.h>
#include <hip/hip_bf16.h>
#include <stdint.h>

#define NHEADS 16
#define DKEY   64
#define DMODEL 1024
#define BATCH  2
#define SEQ    2048

using bf16x8 = __bf16 __attribute__((ext_vector_type(8)));
using bf16x4 = __bf16 __attribute__((ext_vector_type(4)));
using f32x4  = float __attribute__((ext_vector_type(4)));

// global -> LDS async copy, 16B per lane. LDS dest must be the WAVE-UNIFORM
// base; HW adds lane*16 itself (m104/m108). First-launch round-5 validated
// this addressing (absmax 2.4e-4).
__device__ __forceinline__ void gl_lds16(const void* g, void* l) {
  __builtin_amdgcn_global_load_lds(
      (__attribute__((address_space(1))) void*)(uintptr_t)g,
      (__attribute__((address_space(3))) void*)(uint32_t)(uintptr_t)l,
      16, 0, 0);
}

// ---------------------------------------------------------------------------
// W transpose + cast: W[k][n] fp32 -> WT[n][k] bf16. z: 0->Wo,1->Wq,2->Wk,3->Wv
// ---------------------------------------------------------------------------
__global__ __launch_bounds__(256) void wtrans_kernel(
    const float* __restrict__ Wo, const float* __restrict__ Wq,
    const float* __restrict__ Wk, const float* __restrict__ Wv,
    __bf16* __restrict__ WTbase)
{
  const float* W = (blockIdx.z == 0) ? Wo : (blockIdx.z == 1) ? Wq
                   : (blockIdx.z == 2) ? Wk : Wv;
  __bf16* WT = WTbase + (size_t)blockIdx.z * DMODEL * DMODEL;
  __shared__ float tile[64][65];
  const int tid = threadIdx.x;
  const int k0 = blockIdx.x * 64, n0 = blockIdx.y * 64;
  const int cx = tid & 63, ry = tid >> 6;
#pragma unroll
  for (int i = 0; i < 16; ++i) {
    int kl = i * 4 + ry;
    tile[cx][kl] = W[(size_t)(k0 + kl) * DMODEL + n0 + cx];
  }
  __syncthreads();
#pragma unroll
  for (int i = 0; i < 16; ++i) {
    int nl = i * 4 + ry;
    WT[(size_t)(n0 + nl) * DMODEL + k0 + cx] = (__bf16)tile[nl][cx];
  }
}

// ---------------------------------------------------------------------------
// mask (0/1 fp32) -> bitmask, one uint64 per 64 kv positions
// ---------------------------------------------------------------------------
__global__ __launch_bounds__(256) void maskpack_kernel(
    const float* __restrict__ mask, unsigned long long* __restrict__ bits)
{
  const int gtid = blockIdx.x * 256 + threadIdx.x;
  const int w    = gtid >> 6;
  const int lane = threadIdx.x & 63;
  float v = mask[(size_t)w * 64 + lane];
  unsigned long long m = __ballot(v != 0.0f);
  if (lane == 0) bits[w] = m;
}

// ---------------------------------------------------------------------------
// Merged QKV projection GEMM, fp32 A direct. z=0: Q->Qd, z=1: K->Kd
// (head-major [hb][n][64]), z=2: V->Vt ([hb][64][n]). 128x128 tile, BK=32,
// 4 waves. m97-proven schedule: single LDS buffer, stage -> vmcnt(0) ->
// barrier -> compute -> barrier. No cross-iteration prefetch (race-screened
// structures only: round-5 single-barrier dbuf diverged on replay).
// ---------------------------------------------------------------------------
__global__ __launch_bounds__(256, 4) void qkv_gemm_kernel(
    const float* __restrict__ Qf, const float* __restrict__ Kf, const float* __restrict__ Vf,
    const __bf16* __restrict__ WT,
    const float* __restrict__ bq, const float* __restrict__ bk, const float* __restrict__ bv,
    __bf16* __restrict__ Qd, __bf16* __restrict__ Kd, __bf16* __restrict__ Vt)
{
  __shared__ __bf16 sA[128 * 32];
  __shared__ __bf16 sB[128 * 32];
  const int z = blockIdx.z;
  const float* A     = (z == 0) ? Qf : (z == 1) ? Kf : Vf;
  const __bf16* BT   = WT + (size_t)(z + 1) * DMODEL * DMODEL;  // Wq/Wk/Wv
  const float*  bias = (z == 0) ? bq : (z == 1) ? bk : bv;

  const int tid  = threadIdx.x;
  const int lane = tid & 63;
  const int g    = lane >> 4, l15 = lane & 15;
  const int wid  = tid >> 6;
  const int wr   = wid >> 1, wc = wid & 1;
  const int m0   = blockIdx.x * 128, n0 = blockIdx.y * 128;

  const int srow  = tid >> 2;     // 0..63 (+ c2*64)
  const int sslot = tid & 3;

  f32x4 acc[4][4] = {};

  for (int ks = 0; ks < 32; ++ks) {
    const int k0 = ks * 32;
    // A: global fp32 -> reg (issued first so the cvt's wait leaves gl_lds in flight)
    f32x4 a0[2], a1[2];
#pragma unroll
    for (int c2 = 0; c2 < 2; ++c2) {
      const float* p = A + (size_t)(m0 + c2 * 64 + srow) * DMODEL + k0 + sslot * 8;
      a0[c2] = *(const f32x4*)p;
      a1[c2] = *(const f32x4*)(p + 4);
    }
    // B: async gl_lds (wave-uniform dest base, linear layout)
#pragma unroll
    for (int c2 = 0; c2 < 2; ++c2) {
      char* lb = (char*)sB + c2 * 4096 + wid * 1024;
      gl_lds16(BT + (size_t)(n0 + c2 * 64 + srow) * DMODEL + k0 + sslot * 8, lb);
    }
    // A: cvt + ds_write (linear 16B/lane, conflict-free)
#pragma unroll
    for (int c2 = 0; c2 < 2; ++c2) {
      bf16x8 v;
#pragma unroll
      for (int j = 0; j < 4; ++j) { v[j] = (__bf16)a0[c2][j]; v[j + 4] = (__bf16)a1[c2][j]; }
      *(bf16x8*)((char*)sA + (c2 * 64 + srow) * 64 + sslot * 16) = v;
    }
    asm volatile("s_waitcnt vmcnt(0)" ::: "memory");
    __syncthreads();

    bf16x8 af[4], bfr[4];
#pragma unroll
    for (int mt = 0; mt < 4; ++mt)
      af[mt] = *(const bf16x8*)((const char*)sA + (wr * 64 + mt * 16 + l15) * 64 + g * 16);
#pragma unroll
    for (int nt = 0; nt < 4; ++nt)
      bfr[nt] = *(const bf16x8*)((const char*)sB + (wc * 64 + nt * 16 + l15) * 64 + g * 16);
#pragma unroll
    for (int mt = 0; mt < 4; ++mt)
#pragma unroll
      for (int nt = 0; nt < 4; ++nt)
        acc[mt][nt] = __builtin_amdgcn_mfma_f32_16x16x32_bf16(af[mt], bfr[nt], acc[mt][nt], 0, 0, 0);
    __syncthreads();
  }

  // epilogue: D row = g*4+r (m), col = l15 (n)
#pragma unroll
  for (int nt = 0; nt < 4; ++nt) {
    const int gn = n0 + wc * 64 + nt * 16 + l15;
    const float bvv = bias[gn];
    const int h = gn >> 6, d = gn & 63;
#pragma unroll
    for (int mt = 0; mt < 4; ++mt) {
      const int gmb = m0 + wr * 64 + mt * 16 + g * 4;
      const int b = gmb >> 11, nr = gmb & 2047;
      if (z == 2) {
        bf16x4 pk;
#pragma unroll
        for (int r = 0; r < 4; ++r) pk[r] = (__bf16)(acc[mt][nt][r] + bvv);
        *(bf16x4*)(Vt + ((size_t)(h * 2 + b) * DKEY + d) * SEQ + nr) = pk;
      } else {
        __bf16* outp = z ? Kd : Qd;
#pragma unroll
        for (int r = 0; r < 4; ++r)
          outp[((size_t)(h * 2 + b) * SEQ + nr + r) * DKEY + d] = (__bf16)(acc[mt][nt][r] + bvv);
      }
    }
  }
}

// ---------------------------------------------------------------------------
// Output projection: out[4096][1024] fp32 = AO[4096][1024]bf16 @ WTo^T + bo
// 128x64 tile, m97 schedule (single buffer, 2 barriers), gl_lds staging.
// ---------------------------------------------------------------------------
__global__ __launch_bounds__(256, 4) void out_gemm_kernel(
    const __bf16* __restrict__ AO, const __bf16* __restrict__ WTo,
    const float* __restrict__ bo, float* __restrict__ out)
{
  __shared__ __bf16 sA[128 * 32];
  __shared__ __bf16 sB[64 * 32];
  const int tid  = threadIdx.x;
  const int lane = tid & 63;
  const int g    = lane >> 4, l15 = lane & 15;
  const int wid  = tid >> 6;
  const int wr   = wid >> 1, wc = wid & 1;
  const int m0   = blockIdx.x * 128, n0 = blockIdx.y * 64;

  const int srow  = tid >> 2;
  const int sslot = tid & 3;

  f32x4 acc[4][2] = {};

  for (int ks = 0; ks < 32; ++ks) {
    const int k0 = ks * 32;
#pragma unroll
    for (int c2 = 0; c2 < 2; ++c2) {
      char* la = (char*)sA + c2 * 4096 + wid * 1024;
      gl_lds16(AO + (size_t)(m0 + c2 * 64 + srow) * DMODEL + k0 + sslot * 8, la);
    }
    {
      char* lb = (char*)sB + wid * 1024;
      gl_lds16(WTo + (size_t)(n0 + srow) * DMODEL + k0 + sslot * 8, lb);
    }
    asm volatile("s_waitcnt vmcnt(0)" ::: "memory");
    __syncthreads();

    bf16x8 af[4], bfr[2];
#pragma unroll
    for (int mt = 0; mt < 4; ++mt)
      af[mt] = *(const bf16x8*)((const char*)sA + (wr * 64 + mt * 16 + l15) * 64 + g * 16);
#pragma unroll
    for (int nt = 0; nt < 2; ++nt)
      bfr[nt] = *(const bf16x8*)((const char*)sB + (wc * 32 + nt * 16 + l15) * 64 + g * 16);
#pragma unroll
    for (int mt = 0; mt < 4; ++mt)
#pragma unroll
      for (int nt = 0; nt < 2; ++nt)
        acc[mt][nt] = __builtin_amdgcn_mfma_f32_16x16x32_bf16(af[mt], bfr[nt], acc[mt][nt], 0, 0, 0);
    __syncthreads();
  }

#pragma unroll
  for (int nt = 0; nt < 2; ++nt) {
    const int gn = n0 + wc * 32 + nt * 16 + l15;
    const float bvv = bo[gn];
#pragma unroll
    for (int mt = 0; mt < 4; ++mt) {
      const int gmb = m0 + wr * 64 + mt * 16 + g * 4;
#pragma unroll
      for (int r = 0; r < 4; ++r)
        out[(size_t)(gmb + r) * DMODEL + gn] = acc[mt][nt][r] + bvv;
    }
  }
}

// ---------------------------------------------------------------------------
// Flash-style attention. Block = 64 q-rows of one (h,b); 4 waves x 16 rows.
// Quirk (faithful): U = (QK^T/8) * mask -> masked scores 0 (exp=1), so no
// max-subtraction needed. mask batch b' = (h*2+b)>>4.
// m97 schedule: single K/V buffer, stage -> vmcnt(0) -> bar -> compute -> bar.
// K/V staged via gl_lds with per-lane PRE-SWIZZLED global source + linear
// LDS dest (m173 pattern); reads use the same XOR swizzle (round-5 first
// launch validated all addressing).
// ---------------------------------------------------------------------------
__global__ __launch_bounds__(256, 4) void attn_kernel(
    const __bf16* __restrict__ Qd, const __bf16* __restrict__ Kd,
    const __bf16* __restrict__ Vt, const unsigned long long* __restrict__ mbits,
    __bf16* __restrict__ AO)
{
  __shared__ __bf16 sK[64 * 64];
  __shared__ __bf16 sV[64 * 64];
  __shared__ __bf16 sP[4][16 * 64];

  const int tid = threadIdx.x, lane = tid & 63, wid = tid >> 6;
  const int g = lane >> 4, c = lane & 15;
  const int q0 = blockIdx.x * 64;
  const int hb = blockIdx.y;
  const int h = hb >> 1, b = hb & 1;
  const int bp = hb >> 4;

  const __bf16* Qbase = Qd + (size_t)hb * SEQ * DKEY;
  const __bf16* Kbase = Kd + (size_t)hb * SEQ * DKEY;
  const __bf16* Vbase = Vt + (size_t)hb * DKEY * SEQ;

  const int qr = q0 + wid * 16 + c;
  bf16x8 aq[2];
  aq[0] = *(const bf16x8*)(Qbase + (size_t)qr * DKEY + g * 8);
  aq[1] = *(const bf16x8*)(Qbase + (size_t)qr * DKEY + 32 + g * 8);

  f32x4 o[4] = {};
  float rs[4] = {0.f, 0.f, 0.f, 0.f};

  for (int kv0 = 0; kv0 < SEQ; kv0 += 64) {
    // stage K/V tile (8KB each) via gl_lds
#pragma unroll
    for (int c2 = 0; c2 < 2; ++c2) {
      const int ch = c2 * 256 + tid;
      const int row = ch >> 3, sl = ch & 7;
      char* lk = (char*)sK + c2 * 4096 + wid * 1024;
      char* lv = (char*)sV + c2 * 4096 + wid * 1024;
      gl_lds16(Kbase + (size_t)(kv0 + row) * DKEY + ((sl ^ (row & 7)) * 8), lk);
      gl_lds16(Vbase + (size_t)row * SEQ + kv0 + ((sl ^ (row & 7)) * 8), lv);
    }
    asm volatile("s_waitcnt vmcnt(0)" ::: "memory");
    __syncthreads();

    unsigned long long mw[4];
#pragma unroll
    for (int r = 0; r < 4; ++r) {
      int q = q0 + wid * 16 + g * 4 + r;
      mw[r] = mbits[((size_t)bp * SEQ + q) * 32 + (kv0 >> 6)];
    }

    // QK^T -> scale -> mask-multiply -> exp -> P (bf16, per-wave LDS)
#pragma unroll
    for (int t = 0; t < 4; ++t) {
      f32x4 u = {0.f, 0.f, 0.f, 0.f};
#pragma unroll
      for (int kk = 0; kk < 2; ++kk) {
        int row = t * 16 + c;
        bf16x8 kf = *(const bf16x8*)((char*)sK + row * 128 + (((g + kk * 4) ^ (row & 7)) * 16));
        u = __builtin_amdgcn_mfma_f32_16x16x32_bf16(aq[kk], kf, u, 0, 0, 0);
      }
#pragma unroll
      for (int r = 0; r < 4; ++r) {
        int col = t * 16 + c;
        float s = u[r] * 0.125f;
        s = ((mw[r] >> col) & 1ULL) ? s : 0.0f;
        float p = __expf(s);
        rs[r] += p;
        int qrl = g * 4 + r;
        int sp = (col >> 3) ^ (qrl & 7);
        *(__bf16*)((char*)&sP[wid][0] + qrl * 128 + sp * 16 + (col & 7) * 2) = (__bf16)p;
      }
    }
    asm volatile("s_waitcnt lgkmcnt(0)" ::: "memory");  // P writes -> reads (same wave)

    // PV: O += P @ V
    bf16x8 ap[2];
#pragma unroll
    for (int kk = 0; kk < 2; ++kk) {
      int sp = (kk * 4 + g) ^ (c & 7);
      ap[kk] = *(const bf16x8*)((char*)&sP[wid][0] + c * 128 + sp * 16);
    }
    __builtin_amdgcn_s_setprio(1);
#pragma unroll
    for (int dt = 0; dt < 4; ++dt) {
#pragma unroll
      for (int kk = 0; kk < 2; ++kk) {
        int row = dt * 16 + c;
        bf16x8 vf = *(const bf16x8*)((char*)sV + row * 128 + (((kk * 4 + g) ^ (row & 7)) * 16));
        o[dt] = __builtin_amdgcn_mfma_f32_16x16x32_bf16(ap[kk], vf, o[dt], 0, 0, 0);
      }
    }
    __builtin_amdgcn_s_setprio(0);
    __syncthreads();   // reads of sK/sV done before next tile's stage
  }

  // row-sum reduce across the 16-lane group
#pragma unroll
  for (int r = 0; r < 4; ++r) {
    float v = rs[r];
    v += __shfl_xor(v, 1, 16);
    v += __shfl_xor(v, 2, 16);
    v += __shfl_xor(v, 4, 16);
    v += __shfl_xor(v, 8, 16);
    rs[r] = v;
  }

#pragma unroll
  for (int dt = 0; dt < 4; ++dt) {
#pragma unroll
    for (int r = 0; r < 4; ++r) {
      int q = q0 + wid * 16 + g * 4 + r;
      int dk = dt * 16 + c;
      AO[((size_t)b * SEQ + q) * DMODEL + h * 64 + dk] = (__bf16)(o[dt][r] / rs[r]);
    }
  }
}

// ---------------------------------------------------------------------------
extern "C" void kernel_launch(void* const* d_in, const int* in_sizes, int n_in,
                              void* d_out, int out_size, void* d_ws, size_t ws_size,
                              hipStream_t stream)
{
  (void)in_sizes; (void)n_in; (void)out_size; (void)ws_size;
  const float* Q    = (const float*)d_in[0];
  const float* V    = (const float*)d_in[1];   // note: V before K in inputs
  const float* K    = (const float*)d_in[2];
  const float* mask = (const float*)d_in[3];
  const float* Wq   = (const float*)d_in[4];
  const float* bq   = (const float*)d_in[5];
  const float* Wk   = (const float*)d_in[6];
  const float* bk   = (const float*)d_in[7];
  const float* Wv   = (const float*)d_in[8];
  const float* bv   = (const float*)d_in[9];
  const float* Wo   = (const float*)d_in[10];
  const float* bo   = (const float*)d_in[11];
  float* out = (float*)d_out;

  // Workspace: 41 MB total (round-0/1 proven bound).
  char* ws = (char*)d_ws;
  const size_t MB = 1024 * 1024;
  __bf16* WT = (__bf16*)(ws);               // 8MB: [Wo,Wq,Wk,Wv] bf16 [n][k]
  __bf16* AO = (__bf16*)(ws + 8 * MB);      // 8MB [b][n][1024]
  __bf16* Qd = (__bf16*)(ws + 16 * MB);     // 8MB [hb][n][64]
  __bf16* Kd = (__bf16*)(ws + 24 * MB);     // 8MB [hb][n][64]
  __bf16* Vt = (__bf16*)(ws + 32 * MB);     // 8MB [hb][64][n]
  unsigned long long* mbits = (unsigned long long*)(ws + 40 * MB); // 1MB

  wtrans_kernel<<<dim3(16, 16, 4), 256, 0, stream>>>(Wo, Wq, Wk, Wv, WT);
  maskpack_kernel<<<dim3(32768), 256, 0, stream>>>(mask, mbits);
  qkv_gemm_kernel<<<dim3(32, 8, 3), 256, 0, stream>>>(Q, K, V, WT, bq, bk, bv, Qd, Kd, Vt);
  attn_kernel<<<dim3(32, 32), 256, 0, stream>>>(Qd, Kd, Vt, mbits, AO);
  out_gemm_kernel<<<dim3(32, 16), 256, 0, stream>>>(AO, WT, bo, out);
}

// Round 8
// 281.526 us; speedup vs baseline: 1.2212x; 1.0330x over previous
//
#include <hip/hip_runtime.h>
#include <hip/hip_bf16.h>
#include <stdint.h>
#include <math.h>

#define NHEADS 16
#define DKEY   64
#define DMODEL 1024
#define BATCH  2
#define SEQ    2048
// 0.125 (1/sqrt(dk)) * log2(e), folded into Qd so attn uses exp2 directly
#define QSCALE 0.18033688011112042f

using bf16x8 = __bf16 __attribute__((ext_vector_type(8)));
using bf16x4 = __bf16 __attribute__((ext_vector_type(4)));
using f32x4  = float __attribute__((ext_vector_type(4)));

// global -> LDS async copy, 16B per lane. LDS dest must be the WAVE-UNIFORM
// base; HW adds lane*16 itself (m104/m108). R5/R7 validated this addressing.
__device__ __forceinline__ void gl_lds16(const void* g, void* l) {
  __builtin_amdgcn_global_load_lds(
      (__attribute__((address_space(1))) void*)(uintptr_t)g,
      (__attribute__((address_space(3))) void*)(uint32_t)(uintptr_t)l,
      16, 0, 0);
}

// ---------------------------------------------------------------------------
// W transpose + cast: W[k][n] fp32 -> WT[n][k] bf16. z: 0->Wo,1->Wq,2->Wk,3->Wv
// ---------------------------------------------------------------------------
__global__ __launch_bounds__(256) void wtrans_kernel(
    const float* __restrict__ Wo, const float* __restrict__ Wq,
    const float* __restrict__ Wk, const float* __restrict__ Wv,
    __bf16* __restrict__ WTbase)
{
  const float* W = (blockIdx.z == 0) ? Wo : (blockIdx.z == 1) ? Wq
                   : (blockIdx.z == 2) ? Wk : Wv;
  __bf16* WT = WTbase + (size_t)blockIdx.z * DMODEL * DMODEL;
  __shared__ float tile[64][65];
  const int tid = threadIdx.x;
  const int k0 = blockIdx.x * 64, n0 = blockIdx.y * 64;
  const int cx = tid & 63, ry = tid >> 6;
#pragma unroll
  for (int i = 0; i < 16; ++i) {
    int kl = i * 4 + ry;
    tile[cx][kl] = W[(size_t)(k0 + kl) * DMODEL + n0 + cx];
  }
  __syncthreads();
#pragma unroll
  for (int i = 0; i < 16; ++i) {
    int nl = i * 4 + ry;
    WT[(size_t)(n0 + nl) * DMODEL + k0 + cx] = (__bf16)tile[nl][cx];
  }
}

// ---------------------------------------------------------------------------
// mask (0/1 fp32) -> bitmask, one uint64 per 64 kv positions
// ---------------------------------------------------------------------------
__global__ __launch_bounds__(256) void maskpack_kernel(
    const float* __restrict__ mask, unsigned long long* __restrict__ bits)
{
  const int gtid = blockIdx.x * 256 + threadIdx.x;
  const int w    = gtid >> 6;
  const int lane = threadIdx.x & 63;
  float v = mask[(size_t)w * 64 + lane];
  unsigned long long m = __ballot(v != 0.0f);
  if (lane == 0) bits[w] = m;
}

// ---------------------------------------------------------------------------
// Merged QKV projection GEMM, fp32 A direct. z=0: Q->Qd (pre-scaled by
// QSCALE), z=1: K->Kd (head-major [hb][n][64]), z=2: V->Vt ([hb][64][n]).
// 128x128 tile, BK=64 (16 steps of 32 MFMA — halves barrier-drain count vs
// R7's BK=32), 4 waves. m97-proven schedule: single LDS buffer,
// stage -> vmcnt(0) -> barrier -> compute -> barrier. 128B LDS rows need the
// XOR slot swizzle (T2 / G4): B = pre-swizzled gl_lds source + swizzled read;
// A = swizzled ds_write + swizzled read (both-sides rule #21).
// ---------------------------------------------------------------------------
__global__ __launch_bounds__(256, 3) void qkv_gemm_kernel(
    const float* __restrict__ Qf, const float* __restrict__ Kf, const float* __restrict__ Vf,
    const __bf16* __restrict__ WT,
    const float* __restrict__ bq, const float* __restrict__ bk, const float* __restrict__ bv,
    __bf16* __restrict__ Qd, __bf16* __restrict__ Kd, __bf16* __restrict__ Vt)
{
  __shared__ __bf16 sA[128 * 64];   // 16KB, 128B rows, 8 x 16B slots, XOR-swz
  __shared__ __bf16 sB[128 * 64];   // 16KB
  const int z = blockIdx.z;
  const float* A     = (z == 0) ? Qf : (z == 1) ? Kf : Vf;
  const __bf16* BT   = WT + (size_t)(z + 1) * DMODEL * DMODEL;  // Wq/Wk/Wv
  const float*  bias = (z == 0) ? bq : (z == 1) ? bk : bv;

  const int tid  = threadIdx.x;
  const int lane = tid & 63;
  const int g    = lane >> 4, l15 = lane & 15;
  const int wid  = tid >> 6;
  const int wr   = wid >> 1, wc = wid & 1;
  const int m0   = blockIdx.x * 128, n0 = blockIdx.y * 128;

  const int srow8 = tid >> 3;     // 0..31 (+ c4*32)
  const int ssl8  = tid & 7;      // logical 16B slot 0..7

  f32x4 acc[4][4] = {};

  for (int ks = 0; ks < 16; ++ks) {
    const int k0 = ks * 64;
    // A: global fp32 -> reg (issued first; HBM/L2 latency overlaps the gl_lds)
    f32x4 a0[4], a1[4];
#pragma unroll
    for (int c4 = 0; c4 < 4; ++c4) {
      const int row = c4 * 32 + srow8;
      const float* p = A + (size_t)(m0 + row) * DMODEL + k0 + ssl8 * 8;
      a0[c4] = *(const f32x4*)p;
      a1[c4] = *(const f32x4*)(p + 4);
    }
    // B: gl_lds, source pre-swizzled per lane, linear wave-uniform dest
#pragma unroll
    for (int c4 = 0; c4 < 4; ++c4) {
      const int row = c4 * 32 + srow8;
      char* lb = (char*)sB + c4 * 4096 + wid * 1024;
      gl_lds16(BT + (size_t)(n0 + row) * DMODEL + k0 + ((ssl8 ^ (row & 7)) * 8), lb);
    }
    // A: cvt + swizzled ds_write (physical slot p holds logical chunk p^(row&7))
#pragma unroll
    for (int c4 = 0; c4 < 4; ++c4) {
      const int row = c4 * 32 + srow8;
      bf16x8 v;
#pragma unroll
      for (int j = 0; j < 4; ++j) { v[j] = (__bf16)a0[c4][j]; v[j + 4] = (__bf16)a1[c4][j]; }
      *(bf16x8*)((char*)sA + row * 128 + ((ssl8 ^ (row & 7)) * 16)) = v;
    }
    asm volatile("s_waitcnt vmcnt(0)" ::: "memory");
    __syncthreads();

#pragma unroll
    for (int kk = 0; kk < 2; ++kk) {
      bf16x8 af[4], bfr[4];
#pragma unroll
      for (int mt = 0; mt < 4; ++mt) {
        const int row = wr * 64 + mt * 16 + l15;
        af[mt] = *(const bf16x8*)((const char*)sA + row * 128 + (((kk * 4 + g) ^ (row & 7)) * 16));
      }
#pragma unroll
      for (int nt = 0; nt < 4; ++nt) {
        const int row = wc * 64 + nt * 16 + l15;
        bfr[nt] = *(const bf16x8*)((const char*)sB + row * 128 + (((kk * 4 + g) ^ (row & 7)) * 16));
      }
#pragma unroll
      for (int mt = 0; mt < 4; ++mt)
#pragma unroll
        for (int nt = 0; nt < 4; ++nt)
          acc[mt][nt] = __builtin_amdgcn_mfma_f32_16x16x32_bf16(af[mt], bfr[nt], acc[mt][nt], 0, 0, 0);
    }
    __syncthreads();
  }

  // epilogue: D row = g*4+r (m), col = l15 (n). z==0 pre-scales Q by QSCALE.
#pragma unroll
  for (int nt = 0; nt < 4; ++nt) {
    const int gn = n0 + wc * 64 + nt * 16 + l15;
    const float bvv = bias[gn];
    const int h = gn >> 6, d = gn & 63;
#pragma unroll
    for (int mt = 0; mt < 4; ++mt) {
      const int gmb = m0 + wr * 64 + mt * 16 + g * 4;
      const int b = gmb >> 11, nr = gmb & 2047;
      if (z == 2) {
        bf16x4 pk;
#pragma unroll
        for (int r = 0; r < 4; ++r) pk[r] = (__bf16)(acc[mt][nt][r] + bvv);
        *(bf16x4*)(Vt + ((size_t)(h * 2 + b) * DKEY + d) * SEQ + nr) = pk;
      } else if (z == 0) {
#pragma unroll
        for (int r = 0; r < 4; ++r)
          Qd[((size_t)(h * 2 + b) * SEQ + nr + r) * DKEY + d] = (__bf16)((acc[mt][nt][r] + bvv) * QSCALE);
      } else {
#pragma unroll
        for (int r = 0; r < 4; ++r)
          Kd[((size_t)(h * 2 + b) * SEQ + nr + r) * DKEY + d] = (__bf16)(acc[mt][nt][r] + bvv);
      }
    }
  }
}

// ---------------------------------------------------------------------------
// Output projection: out[4096][1024] fp32 = AO[4096][1024]bf16 @ WTo^T + bo
// 128x64 tile, BK=64 (16 steps), m97 schedule, gl_lds staging, XOR swizzle.
// ---------------------------------------------------------------------------
__global__ __launch_bounds__(256, 4) void out_gemm_kernel(
    const __bf16* __restrict__ AO, const __bf16* __restrict__ WTo,
    const float* __restrict__ bo, float* __restrict__ out)
{
  __shared__ __bf16 sA[128 * 64];   // 16KB
  __shared__ __bf16 sB[64 * 64];    // 8KB
  const int tid  = threadIdx.x;
  const int lane = tid & 63;
  const int g    = lane >> 4, l15 = lane & 15;
  const int wid  = tid >> 6;
  const int wr   = wid >> 1, wc = wid & 1;
  const int m0   = blockIdx.x * 128, n0 = blockIdx.y * 64;

  const int srow8 = tid >> 3;
  const int ssl8  = tid & 7;

  f32x4 acc[4][2] = {};

  for (int ks = 0; ks < 16; ++ks) {
    const int k0 = ks * 64;
#pragma unroll
    for (int c4 = 0; c4 < 4; ++c4) {
      const int row = c4 * 32 + srow8;
      char* la = (char*)sA + c4 * 4096 + wid * 1024;
      gl_lds16(AO + (size_t)(m0 + row) * DMODEL + k0 + ((ssl8 ^ (row & 7)) * 8), la);
    }
#pragma unroll
    for (int c2 = 0; c2 < 2; ++c2) {
      const int row = c2 * 32 + srow8;
      char* lb = (char*)sB + c2 * 4096 + wid * 1024;
      gl_lds16(WTo + (size_t)(n0 + row) * DMODEL + k0 + ((ssl8 ^ (row & 7)) * 8), lb);
    }
    asm volatile("s_waitcnt vmcnt(0)" ::: "memory");
    __syncthreads();

#pragma unroll
    for (int kk = 0; kk < 2; ++kk) {
      bf16x8 af[4], bfr[2];
#pragma unroll
      for (int mt = 0; mt < 4; ++mt) {
        const int row = wr * 64 + mt * 16 + l15;
        af[mt] = *(const bf16x8*)((const char*)sA + row * 128 + (((kk * 4 + g) ^ (row & 7)) * 16));
      }
#pragma unroll
      for (int nt = 0; nt < 2; ++nt) {
        const int row = wc * 32 + nt * 16 + l15;
        bfr[nt] = *(const bf16x8*)((const char*)sB + row * 128 + (((kk * 4 + g) ^ (row & 7)) * 16));
      }
#pragma unroll
      for (int mt = 0; mt < 4; ++mt)
#pragma unroll
        for (int nt = 0; nt < 2; ++nt)
          acc[mt][nt] = __builtin_amdgcn_mfma_f32_16x16x32_bf16(af[mt], bfr[nt], acc[mt][nt], 0, 0, 0);
    }
    __syncthreads();
  }

#pragma unroll
  for (int nt = 0; nt < 2; ++nt) {
    const int gn = n0 + wc * 32 + nt * 16 + l15;
    const float bvv = bo[gn];
#pragma unroll
    for (int mt = 0; mt < 4; ++mt) {
      const int gmb = m0 + wr * 64 + mt * 16 + g * 4;
#pragma unroll
      for (int r = 0; r < 4; ++r)
        out[(size_t)(gmb + r) * DMODEL + gn] = acc[mt][nt][r] + bvv;
    }
  }
}

// ---------------------------------------------------------------------------
// Flash-style attention. Block = 64 q-rows of one (h,b); 4 waves x 16 rows.
// Quirk (faithful): U = (QK^T/8) * mask -> masked scores 0 (exp=1), so no
// max-subtraction needed. mask batch b' = (h*2+b)>>4.
// Q pre-scaled by 0.125*log2e in projection -> p = exp2(u) directly (saves
// 2 VALU/element on the critical VALU-bound path; VALUBusy 48% @ R7).
// m97 schedule: single K/V buffer, stage -> vmcnt(0) -> bar -> compute -> bar.
// ---------------------------------------------------------------------------
__global__ __launch_bounds__(256, 4) void attn_kernel(
    const __bf16* __restrict__ Qd, const __bf16* __restrict__ Kd,
    const __bf16* __restrict__ Vt, const unsigned long long* __restrict__ mbits,
    __bf16* __restrict__ AO)
{
  __shared__ __bf16 sK[64 * 64];
  __shared__ __bf16 sV[64 * 64];
  __shared__ __bf16 sP[4][16 * 64];

  const int tid = threadIdx.x, lane = tid & 63, wid = tid >> 6;
  const int g = lane >> 4, c = lane & 15;
  const int q0 = blockIdx.x * 64;
  const int hb = blockIdx.y;
  const int h = hb >> 1, b = hb & 1;
  const int bp = hb >> 4;

  const __bf16* Qbase = Qd + (size_t)hb * SEQ * DKEY;
  const __bf16* Kbase = Kd + (size_t)hb * SEQ * DKEY;
  const __bf16* Vbase = Vt + (size_t)hb * DKEY * SEQ;

  const int qr = q0 + wid * 16 + c;
  bf16x8 aq[2];
  aq[0] = *(const bf16x8*)(Qbase + (size_t)qr * DKEY + g * 8);
  aq[1] = *(const bf16x8*)(Qbase + (size_t)qr * DKEY + 32 + g * 8);

  f32x4 o[4] = {};
  float rs[4] = {0.f, 0.f, 0.f, 0.f};

  for (int kv0 = 0; kv0 < SEQ; kv0 += 64) {
    // stage K/V tile (8KB each) via gl_lds, pre-swizzled source
#pragma unroll
    for (int c2 = 0; c2 < 2; ++c2) {
      const int ch = c2 * 256 + tid;
      const int row = ch >> 3, sl = ch & 7;
      char* lk = (char*)sK + c2 * 4096 + wid * 1024;
      char* lv = (char*)sV + c2 * 4096 + wid * 1024;
      gl_lds16(Kbase + (size_t)(kv0 + row) * DKEY + ((sl ^ (row & 7)) * 8), lk);
      gl_lds16(Vbase + (size_t)row * SEQ + kv0 + ((sl ^ (row & 7)) * 8), lv);
    }
    asm volatile("s_waitcnt vmcnt(0)" ::: "memory");
    __syncthreads();

    unsigned long long mw[4];
#pragma unroll
    for (int r = 0; r < 4; ++r) {
      int q = q0 + wid * 16 + g * 4 + r;
      mw[r] = mbits[((size_t)bp * SEQ + q) * 32 + (kv0 >> 6)];
    }

    // QK^T -> mask-multiply -> exp2 -> P (bf16, per-wave LDS)
#pragma unroll
    for (int t = 0; t < 4; ++t) {
      f32x4 u = {0.f, 0.f, 0.f, 0.f};
#pragma unroll
      for (int kk = 0; kk < 2; ++kk) {
        int row = t * 16 + c;
        bf16x8 kf = *(const bf16x8*)((char*)sK + row * 128 + (((g + kk * 4) ^ (row & 7)) * 16));
        u = __builtin_amdgcn_mfma_f32_16x16x32_bf16(aq[kk], kf, u, 0, 0, 0);
      }
#pragma unroll
      for (int r = 0; r < 4; ++r) {
        int col = t * 16 + c;
        float s = ((mw[r] >> col) & 1ULL) ? u[r] : 0.0f;  // faithful mask-mult
        float p = exp2f(s);                               // masked -> 2^0 = 1
        rs[r] += p;
        int qrl = g * 4 + r;
        int sp = (col >> 3) ^ (qrl & 7);
        *(__bf16*)((char*)&sP[wid][0] + qrl * 128 + sp * 16 + (col & 7) * 2) = (__bf16)p;
      }
    }
    asm volatile("s_waitcnt lgkmcnt(0)" ::: "memory");  // P writes -> reads (same wave)

    // PV: O += P @ V
    bf16x8 ap[2];
#pragma unroll
    for (int kk = 0; kk < 2; ++kk) {
      int sp = (kk * 4 + g) ^ (c & 7);
      ap[kk] = *(const bf16x8*)((char*)&sP[wid][0] + c * 128 + sp * 16);
    }
    __builtin_amdgcn_s_setprio(1);
#pragma unroll
    for (int dt = 0; dt < 4; ++dt) {
#pragma unroll
      for (int kk = 0; kk < 2; ++kk) {
        int row = dt * 16 + c;
        bf16x8 vf = *(const bf16x8*)((char*)sV + row * 128 + (((kk * 4 + g) ^ (row & 7)) * 16));
        o[dt] = __builtin_amdgcn_mfma_f32_16x16x32_bf16(ap[kk], vf, o[dt], 0, 0, 0);
      }
    }
    __builtin_amdgcn_s_setprio(0);
    __syncthreads();   // reads of sK/sV done before next tile's stage
  }

  // row-sum reduce across the 16-lane group
#pragma unroll
  for (int r = 0; r < 4; ++r) {
    float v = rs[r];
    v += __shfl_xor(v, 1, 16);
    v += __shfl_xor(v, 2, 16);
    v += __shfl_xor(v, 4, 16);
    v += __shfl_xor(v, 8, 16);
    rs[r] = v;
  }

#pragma unroll
  for (int dt = 0; dt < 4; ++dt) {
#pragma unroll
    for (int r = 0; r < 4; ++r) {
      int q = q0 + wid * 16 + g * 4 + r;
      int dk = dt * 16 + c;
      AO[((size_t)b * SEQ + q) * DMODEL + h * 64 + dk] = (__bf16)(o[dt][r] / rs[r]);
    }
  }
}

// ---------------------------------------------------------------------------
extern "C" void kernel_launch(void* const* d_in, const int* in_sizes, int n_in,
                              void* d_out, int out_size, void* d_ws, size_t ws_size,
                              hipStream_t stream)
{
  (void)in_sizes; (void)n_in; (void)out_size; (void)ws_size;
  const float* Q    = (const float*)d_in[0];
  const float* V    = (const float*)d_in[1];   // note: V before K in inputs
  const float* K    = (const float*)d_in[2];
  const float* mask = (const float*)d_in[3];
  const float* Wq   = (const float*)d_in[4];
  const float* bq   = (const float*)d_in[5];
  const float* Wk   = (const float*)d_in[6];
  const float* bk   = (const float*)d_in[7];
  const float* Wv   = (const float*)d_in[8];
  const float* bv   = (const float*)d_in[9];
  const float* Wo   = (const float*)d_in[10];
  const float* bo   = (const float*)d_in[11];
  float* out = (float*)d_out;

  // Workspace: 41 MB total (proven bound).
  char* ws = (char*)d_ws;
  const size_t MB = 1024 * 1024;
  __bf16* WT = (__bf16*)(ws);               // 8MB: [Wo,Wq,Wk,Wv] bf16 [n][k]
  __bf16* AO = (__bf16*)(ws + 8 * MB);      // 8MB [b][n][1024]
  __bf16* Qd = (__bf16*)(ws + 16 * MB);     // 8MB [hb][n][64] (pre-scaled)
  __bf16* Kd = (__bf16*)(ws + 24 * MB);     // 8MB [hb][n][64]
  __bf16* Vt = (__bf16*)(ws + 32 * MB);     // 8MB [hb][64][n]
  unsigned long long* mbits = (unsigned long long*)(ws + 40 * MB); // 1MB

  wtrans_kernel<<<dim3(16, 16, 4), 256, 0, stream>>>(Wo, Wq, Wk, Wv, WT);
  maskpack_kernel<<<dim3(32768), 256, 0, stream>>>(mask, mbits);
  qkv_gemm_kernel<<<dim3(32, 8, 3), 256, 0, stream>>>(Q, K, V, WT, bq, bk, bv, Qd, Kd, Vt);
  attn_kernel<<<dim3(32, 32), 256, 0, stream>>>(Qd, Kd, Vt, mbits, AO);
  out_gemm_kernel<<<dim3(32, 16), 256, 0, stream>>>(AO, WT, bo, out);
}

// Round 9
// 270.788 us; speedup vs baseline: 1.2696x; 1.0397x over previous
//
#include <hip/hip_runtime.h>
#include <hip/hip_bf16.h>
#include <stdint.h>
#include <math.h>

#define NHEADS 16
#define DKEY   64
#define DMODEL 1024
#define BATCH  2
#define SEQ    2048
// 0.125 (1/sqrt(dk)) * log2(e), folded into Qd so attn uses v_exp_f32 directly
#define QSCALE 0.18033688011112042f

using bf16x8 = __bf16 __attribute__((ext_vector_type(8)));
using bf16x4 = __bf16 __attribute__((ext_vector_type(4)));
using f32x4  = float __attribute__((ext_vector_type(4)));

// global -> LDS async copy, 16B per lane. LDS dest must be the WAVE-UNIFORM
// base; HW adds lane*16 itself (m104/m108). R5/R7/R8 validated this addressing.
__device__ __forceinline__ void gl_lds16(const void* g, void* l) {
  __builtin_amdgcn_global_load_lds(
      (__attribute__((address_space(1))) void*)(uintptr_t)g,
      (__attribute__((address_space(3))) void*)(uint32_t)(uintptr_t)l,
      16, 0, 0);
}

// ---------------------------------------------------------------------------
// W transpose + cast: W[k][n] fp32 -> WT[n][k] bf16. z: 0->Wo,1->Wq,2->Wk,3->Wv
// ---------------------------------------------------------------------------
__global__ __launch_bounds__(256) void wtrans_kernel(
    const float* __restrict__ Wo, const float* __restrict__ Wq,
    const float* __restrict__ Wk, const float* __restrict__ Wv,
    __bf16* __restrict__ WTbase)
{
  const float* W = (blockIdx.z == 0) ? Wo : (blockIdx.z == 1) ? Wq
                   : (blockIdx.z == 2) ? Wk : Wv;
  __bf16* WT = WTbase + (size_t)blockIdx.z * DMODEL * DMODEL;
  __shared__ float tile[64][65];
  const int tid = threadIdx.x;
  const int k0 = blockIdx.x * 64, n0 = blockIdx.y * 64;
  const int cx = tid & 63, ry = tid >> 6;
#pragma unroll
  for (int i = 0; i < 16; ++i) {
    int kl = i * 4 + ry;
    tile[cx][kl] = W[(size_t)(k0 + kl) * DMODEL + n0 + cx];
  }
  __syncthreads();
#pragma unroll
  for (int i = 0; i < 16; ++i) {
    int nl = i * 4 + ry;
    WT[(size_t)(n0 + nl) * DMODEL + k0 + cx] = (__bf16)tile[nl][cx];
  }
}

// ---------------------------------------------------------------------------
// mask (0/1 fp32) -> bitmask, one uint64 per 64 kv positions
// ---------------------------------------------------------------------------
__global__ __launch_bounds__(256) void maskpack_kernel(
    const float* __restrict__ mask, unsigned long long* __restrict__ bits)
{
  const int gtid = blockIdx.x * 256 + threadIdx.x;
  const int w    = gtid >> 6;
  const int lane = threadIdx.x & 63;
  float v = mask[(size_t)w * 64 + lane];
  unsigned long long m = __ballot(v != 0.0f);
  if (lane == 0) bits[w] = m;
}

// ---------------------------------------------------------------------------
// Merged QKV projection GEMM, fp32 A direct. z=0: Q->Qd (pre-scaled by
// QSCALE), z=1: K->Kd (head-major [hb][n][64]), z=2: V->Vt ([hb][64][n]).
// 128x128 tile, BK=64 (16 steps of 32 MFMA), 4 waves. m97-proven schedule:
// single LDS buffer, stage -> vmcnt(0) -> barrier -> compute -> barrier.
// 128B LDS rows with XOR slot swizzle (both-sides rule #21): validated R8.
// ---------------------------------------------------------------------------
__global__ __launch_bounds__(256, 3) void qkv_gemm_kernel(
    const float* __restrict__ Qf, const float* __restrict__ Kf, const float* __restrict__ Vf,
    const __bf16* __restrict__ WT,
    const float* __restrict__ bq, const float* __restrict__ bk, const float* __restrict__ bv,
    __bf16* __restrict__ Qd, __bf16* __restrict__ Kd, __bf16* __restrict__ Vt)
{
  __shared__ __bf16 sA[128 * 64];   // 16KB, 128B rows, 8 x 16B slots, XOR-swz
  __shared__ __bf16 sB[128 * 64];   // 16KB
  const int z = blockIdx.z;
  const float* A     = (z == 0) ? Qf : (z == 1) ? Kf : Vf;
  const __bf16* BT   = WT + (size_t)(z + 1) * DMODEL * DMODEL;  // Wq/Wk/Wv
  const float*  bias = (z == 0) ? bq : (z == 1) ? bk : bv;

  const int tid  = threadIdx.x;
  const int lane = tid & 63;
  const int g    = lane >> 4, l15 = lane & 15;
  const int wid  = tid >> 6;
  const int wr   = wid >> 1, wc = wid & 1;
  const int m0   = blockIdx.x * 128, n0 = blockIdx.y * 128;

  const int srow8 = tid >> 3;     // 0..31 (+ c4*32)
  const int ssl8  = tid & 7;      // logical 16B slot 0..7

  f32x4 acc[4][4] = {};

  for (int ks = 0; ks < 16; ++ks) {
    const int k0 = ks * 64;
    // A: global fp32 -> reg (issued first; HBM/L2 latency overlaps the gl_lds)
    f32x4 a0[4], a1[4];
#pragma unroll
    for (int c4 = 0; c4 < 4; ++c4) {
      const int row = c4 * 32 + srow8;
      const float* p = A + (size_t)(m0 + row) * DMODEL + k0 + ssl8 * 8;
      a0[c4] = *(const f32x4*)p;
      a1[c4] = *(const f32x4*)(p + 4);
    }
    // B: gl_lds, source pre-swizzled per lane, linear wave-uniform dest
#pragma unroll
    for (int c4 = 0; c4 < 4; ++c4) {
      const int row = c4 * 32 + srow8;
      char* lb = (char*)sB + c4 * 4096 + wid * 1024;
      gl_lds16(BT + (size_t)(n0 + row) * DMODEL + k0 + ((ssl8 ^ (row & 7)) * 8), lb);
    }
    // A: cvt + swizzled ds_write (physical slot p holds logical chunk p^(row&7))
#pragma unroll
    for (int c4 = 0; c4 < 4; ++c4) {
      const int row = c4 * 32 + srow8;
      bf16x8 v;
#pragma unroll
      for (int j = 0; j < 4; ++j) { v[j] = (__bf16)a0[c4][j]; v[j + 4] = (__bf16)a1[c4][j]; }
      *(bf16x8*)((char*)sA + row * 128 + ((ssl8 ^ (row & 7)) * 16)) = v;
    }
    asm volatile("s_waitcnt vmcnt(0)" ::: "memory");
    __syncthreads();

#pragma unroll
    for (int kk = 0; kk < 2; ++kk) {
      bf16x8 af[4], bfr[4];
#pragma unroll
      for (int mt = 0; mt < 4; ++mt) {
        const int row = wr * 64 + mt * 16 + l15;
        af[mt] = *(const bf16x8*)((const char*)sA + row * 128 + (((kk * 4 + g) ^ (row & 7)) * 16));
      }
#pragma unroll
      for (int nt = 0; nt < 4; ++nt) {
        const int row = wc * 64 + nt * 16 + l15;
        bfr[nt] = *(const bf16x8*)((const char*)sB + row * 128 + (((kk * 4 + g) ^ (row & 7)) * 16));
      }
#pragma unroll
      for (int mt = 0; mt < 4; ++mt)
#pragma unroll
        for (int nt = 0; nt < 4; ++nt)
          acc[mt][nt] = __builtin_amdgcn_mfma_f32_16x16x32_bf16(af[mt], bfr[nt], acc[mt][nt], 0, 0, 0);
    }
    __syncthreads();
  }

  // epilogue: D row = g*4+r (m), col = l15 (n). z==0 pre-scales Q by QSCALE.
#pragma unroll
  for (int nt = 0; nt < 4; ++nt) {
    const int gn = n0 + wc * 64 + nt * 16 + l15;
    const float bvv = bias[gn];
    const int h = gn >> 6, d = gn & 63;
#pragma unroll
    for (int mt = 0; mt < 4; ++mt) {
      const int gmb = m0 + wr * 64 + mt * 16 + g * 4;
      const int b = gmb >> 11, nr = gmb & 2047;
      if (z == 2) {
        bf16x4 pk;
#pragma unroll
        for (int r = 0; r < 4; ++r) pk[r] = (__bf16)(acc[mt][nt][r] + bvv);
        *(bf16x4*)(Vt + ((size_t)(h * 2 + b) * DKEY + d) * SEQ + nr) = pk;
      } else if (z == 0) {
#pragma unroll
        for (int r = 0; r < 4; ++r)
          Qd[((size_t)(h * 2 + b) * SEQ + nr + r) * DKEY + d] = (__bf16)((acc[mt][nt][r] + bvv) * QSCALE);
      } else {
#pragma unroll
        for (int r = 0; r < 4; ++r)
          Kd[((size_t)(h * 2 + b) * SEQ + nr + r) * DKEY + d] = (__bf16)(acc[mt][nt][r] + bvv);
      }
    }
  }
}

// ---------------------------------------------------------------------------
// Output projection: out[4096][1024] fp32 = AO[4096][1024]bf16 @ WTo^T + bo
// 128x64 tile, BK=64 (16 steps), m97 schedule, gl_lds staging, XOR swizzle.
// ---------------------------------------------------------------------------
__global__ __launch_bounds__(256, 4) void out_gemm_kernel(
    const __bf16* __restrict__ AO, const __bf16* __restrict__ WTo,
    const float* __restrict__ bo, float* __restrict__ out)
{
  __shared__ __bf16 sA[128 * 64];   // 16KB
  __shared__ __bf16 sB[64 * 64];    // 8KB
  const int tid  = threadIdx.x;
  const int lane = tid & 63;
  const int g    = lane >> 4, l15 = lane & 15;
  const int wid  = tid >> 6;
  const int wr   = wid >> 1, wc = wid & 1;
  const int m0   = blockIdx.x * 128, n0 = blockIdx.y * 64;

  const int srow8 = tid >> 3;
  const int ssl8  = tid & 7;

  f32x4 acc[4][2] = {};

  for (int ks = 0; ks < 16; ++ks) {
    const int k0 = ks * 64;
#pragma unroll
    for (int c4 = 0; c4 < 4; ++c4) {
      const int row = c4 * 32 + srow8;
      char* la = (char*)sA + c4 * 4096 + wid * 1024;
      gl_lds16(AO + (size_t)(m0 + row) * DMODEL + k0 + ((ssl8 ^ (row & 7)) * 8), la);
    }
#pragma unroll
    for (int c2 = 0; c2 < 2; ++c2) {
      const int row = c2 * 32 + srow8;
      char* lb = (char*)sB + c2 * 4096 + wid * 1024;
      gl_lds16(WTo + (size_t)(n0 + row) * DMODEL + k0 + ((ssl8 ^ (row & 7)) * 8), lb);
    }
    asm volatile("s_waitcnt vmcnt(0)" ::: "memory");
    __syncthreads();

#pragma unroll
    for (int kk = 0; kk < 2; ++kk) {
      bf16x8 af[4], bfr[2];
#pragma unroll
      for (int mt = 0; mt < 4; ++mt) {
        const int row = wr * 64 + mt * 16 + l15;
        af[mt] = *(const bf16x8*)((const char*)sA + row * 128 + (((kk * 4 + g) ^ (row & 7)) * 16));
      }
#pragma unroll
      for (int nt = 0; nt < 2; ++nt) {
        const int row = wc * 32 + nt * 16 + l15;
        bfr[nt] = *(const bf16x8*)((const char*)sB + row * 128 + (((kk * 4 + g) ^ (row & 7)) * 16));
      }
#pragma unroll
      for (int mt = 0; mt < 4; ++mt)
#pragma unroll
        for (int nt = 0; nt < 2; ++nt)
          acc[mt][nt] = __builtin_amdgcn_mfma_f32_16x16x32_bf16(af[mt], bfr[nt], acc[mt][nt], 0, 0, 0);
    }
    __syncthreads();
  }

#pragma unroll
  for (int nt = 0; nt < 2; ++nt) {
    const int gn = n0 + wc * 32 + nt * 16 + l15;
    const float bvv = bo[gn];
#pragma unroll
    for (int mt = 0; mt < 4; ++mt) {
      const int gmb = m0 + wr * 64 + mt * 16 + g * 4;
#pragma unroll
      for (int r = 0; r < 4; ++r)
        out[(size_t)(gmb + r) * DMODEL + gn] = acc[mt][nt][r] + bvv;
    }
  }
}

// ---------------------------------------------------------------------------
// Flash-style attention. Block = 64 q-rows of one (h,b); 4 waves x 16 rows.
// Quirk (faithful): U = (QK^T/8) * mask -> masked scores 0 (exp=1), so no
// max-subtraction needed. mask batch b' = (h*2+b)>>4.
// Q pre-scaled by 0.125*log2e -> p = v_exp_f32(u) via __builtin_amdgcn_exp2f.
// (R8 post-mortem: exp2f libm call was PRECISE ocml -> +8 VALU/elem; the raw
// instruction is the whole point of the pre-fold.)
// m97 schedule: single K/V buffer, stage -> vmcnt(0) -> bar -> compute -> bar.
// ---------------------------------------------------------------------------
__global__ __launch_bounds__(256, 4) void attn_kernel(
    const __bf16* __restrict__ Qd, const __bf16* __restrict__ Kd,
    const __bf16* __restrict__ Vt, const unsigned long long* __restrict__ mbits,
    __bf16* __restrict__ AO)
{
  __shared__ __bf16 sK[64 * 64];
  __shared__ __bf16 sV[64 * 64];
  __shared__ __bf16 sP[4][16 * 64];

  const int tid = threadIdx.x, lane = tid & 63, wid = tid >> 6;
  const int g = lane >> 4, c = lane & 15;
  const int q0 = blockIdx.x * 64;
  const int hb = blockIdx.y;
  const int h = hb >> 1, b = hb & 1;
  const int bp = hb >> 4;

  const __bf16* Qbase = Qd + (size_t)hb * SEQ * DKEY;
  const __bf16* Kbase = Kd + (size_t)hb * SEQ * DKEY;
  const __bf16* Vbase = Vt + (size_t)hb * DKEY * SEQ;

  const int qr = q0 + wid * 16 + c;
  bf16x8 aq[2];
  aq[0] = *(const bf16x8*)(Qbase + (size_t)qr * DKEY + g * 8);
  aq[1] = *(const bf16x8*)(Qbase + (size_t)qr * DKEY + 32 + g * 8);

  f32x4 o[4] = {};
  float rs[4] = {0.f, 0.f, 0.f, 0.f};

  for (int kv0 = 0; kv0 < SEQ; kv0 += 64) {
    // stage K/V tile (8KB each) via gl_lds, pre-swizzled source
#pragma unroll
    for (int c2 = 0; c2 < 2; ++c2) {
      const int ch = c2 * 256 + tid;
      const int row = ch >> 3, sl = ch & 7;
      char* lk = (char*)sK + c2 * 4096 + wid * 1024;
      char* lv = (char*)sV + c2 * 4096 + wid * 1024;
      gl_lds16(Kbase + (size_t)(kv0 + row) * DKEY + ((sl ^ (row & 7)) * 8), lk);
      gl_lds16(Vbase + (size_t)row * SEQ + kv0 + ((sl ^ (row & 7)) * 8), lv);
    }
    asm volatile("s_waitcnt vmcnt(0)" ::: "memory");
    __syncthreads();

    unsigned long long mw[4];
#pragma unroll
    for (int r = 0; r < 4; ++r) {
      int q = q0 + wid * 16 + g * 4 + r;
      mw[r] = mbits[((size_t)bp * SEQ + q) * 32 + (kv0 >> 6)];
    }

    // QK^T -> mask-multiply -> v_exp_f32 -> P (bf16, per-wave LDS)
#pragma unroll
    for (int t = 0; t < 4; ++t) {
      f32x4 u = {0.f, 0.f, 0.f, 0.f};
#pragma unroll
      for (int kk = 0; kk < 2; ++kk) {
        int row = t * 16 + c;
        bf16x8 kf = *(const bf16x8*)((char*)sK + row * 128 + (((g + kk * 4) ^ (row & 7)) * 16));
        u = __builtin_amdgcn_mfma_f32_16x16x32_bf16(aq[kk], kf, u, 0, 0, 0);
      }
#pragma unroll
      for (int r = 0; r < 4; ++r) {
        int col = t * 16 + c;
        float s = ((mw[r] >> col) & 1ULL) ? u[r] : 0.0f;  // faithful mask-mult
        float p = __builtin_amdgcn_exp2f(s);              // raw v_exp_f32; 2^0=1
        rs[r] += p;
        int qrl = g * 4 + r;
        int sp = (col >> 3) ^ (qrl & 7);
        *(__bf16*)((char*)&sP[wid][0] + qrl * 128 + sp * 16 + (col & 7) * 2) = (__bf16)p;
      }
    }
    asm volatile("s_waitcnt lgkmcnt(0)" ::: "memory");  // P writes -> reads (same wave)

    // PV: O += P @ V
    bf16x8 ap[2];
#pragma unroll
    for (int kk = 0; kk < 2; ++kk) {
      int sp = (kk * 4 + g) ^ (c & 7);
      ap[kk] = *(const bf16x8*)((char*)&sP[wid][0] + c * 128 + sp * 16);
    }
    __builtin_amdgcn_s_setprio(1);
#pragma unroll
    for (int dt = 0; dt < 4; ++dt) {
#pragma unroll
      for (int kk = 0; kk < 2; ++kk) {
        int row = dt * 16 + c;
        bf16x8 vf = *(const bf16x8*)((char*)sV + row * 128 + (((kk * 4 + g) ^ (row & 7)) * 16));
        o[dt] = __builtin_amdgcn_mfma_f32_16x16x32_bf16(ap[kk], vf, o[dt], 0, 0, 0);
      }
    }
    __builtin_amdgcn_s_setprio(0);
    __syncthreads();   // reads of sK/sV done before next tile's stage
  }

  // row-sum reduce across the 16-lane group
#pragma unroll
  for (int r = 0; r < 4; ++r) {
    float v = rs[r];
    v += __shfl_xor(v, 1, 16);
    v += __shfl_xor(v, 2, 16);
    v += __shfl_xor(v, 4, 16);
    v += __shfl_xor(v, 8, 16);
    rs[r] = v;
  }

#pragma unroll
  for (int dt = 0; dt < 4; ++dt) {
#pragma unroll
    for (int r = 0; r < 4; ++r) {
      int q = q0 + wid * 16 + g * 4 + r;
      int dk = dt * 16 + c;
      AO[((size_t)b * SEQ + q) * DMODEL + h * 64 + dk] = (__bf16)(o[dt][r] / rs[r]);
    }
  }
}

// ---------------------------------------------------------------------------
extern "C" void kernel_launch(void* const* d_in, const int* in_sizes, int n_in,
                              void* d_out, int out_size, void* d_ws, size_t ws_size,
                              hipStream_t stream)
{
  (void)in_sizes; (void)n_in; (void)out_size; (void)ws_size;
  const float* Q    = (const float*)d_in[0];
  const float* V    = (const float*)d_in[1];   // note: V before K in inputs
  const float* K    = (const float*)d_in[2];
  const float* mask = (const float*)d_in[3];
  const float* Wq   = (const float*)d_in[4];
  const float* bq   = (const float*)d_in[5];
  const float* Wk   = (const float*)d_in[6];
  const float* bk   = (const float*)d_in[7];
  const float* Wv   = (const float*)d_in[8];
  const float* bv   = (const float*)d_in[9];
  const float* Wo   = (const float*)d_in[10];
  const float* bo   = (const float*)d_in[11];
  float* out = (float*)d_out;

  // Workspace: 41 MB total (proven bound).
  char* ws = (char*)d_ws;
  const size_t MB = 1024 * 1024;
  __bf16* WT = (__bf16*)(ws);               // 8MB: [Wo,Wq,Wk,Wv] bf16 [n][k]
  __bf16* AO = (__bf16*)(ws + 8 * MB);      // 8MB [b][n][1024]
  __bf16* Qd = (__bf16*)(ws + 16 * MB);     // 8MB [hb][n][64] (pre-scaled)
  __bf16* Kd = (__bf16*)(ws + 24 * MB);     // 8MB [hb][n][64]
  __bf16* Vt = (__bf16*)(ws + 32 * MB);     // 8MB [hb][64][n]
  unsigned long long* mbits = (unsigned long long*)(ws + 40 * MB); // 1MB

  wtrans_kernel<<<dim3(16, 16, 4), 256, 0, stream>>>(Wo, Wq, Wk, Wv, WT);
  maskpack_kernel<<<dim3(32768), 256, 0, stream>>>(mask, mbits);
  qkv_gemm_kernel<<<dim3(32, 8, 3), 256, 0, stream>>>(Q, K, V, WT, bq, bk, bv, Qd, Kd, Vt);
  attn_kernel<<<dim3(32, 32), 256, 0, stream>>>(Qd, Kd, Vt, mbits, AO);
  out_gemm_kernel<<<dim3(32, 16), 256, 0, stream>>>(AO, WT, bo, out);
}